// Round 1
// baseline (269.558 us; speedup 1.0000x reference)
//
#include <hip/hip_runtime.h>
#include <math.h>

// Problem constants (static shapes per reference)
#define KP 16384
#define DP 2048
#define THRESH 0.5f
#define DECAY 0.99f

// ws float layout:
// [2]  (int) idxMin  = argmin(usages)
// [3]  (int) flag    = 1 evict, 0 ema
// [4]  max_all (max of logits)
// [5]  sumexp_all (ema softmax denom, exp(l - max_all))
// [6]  u
// [7]  zz = ||z||^2
// [8          .. 8+K)    logits
// [8+K        .. 8+2K)   zp (z . p_row)
// [8+2K       .. 8+3K)   pp (||p_row||^2)
// [8+3K       .. 8+4K)   logits2 (ema path only)
// total: (8 + 4*16384)*4 = 262176 bytes

typedef float f4 __attribute__((ext_vector_type(4)));
typedef float f2 __attribute__((ext_vector_type(2)));

__device__ __forceinline__ float waveReduceSum(float v) {
    #pragma unroll
    for (int m = 32; m >= 1; m >>= 1) v += __shfl_xor(v, m, 64);
    return v;
}

__device__ __forceinline__ unsigned int fkey(float v) {
    // monotone float->uint key (order-preserving for all finite floats)
    unsigned int b = __float_as_uint(v);
    return (b & 0x80000000u) ? ~b : (b | 0x80000000u);
}
__device__ __forceinline__ float fkey_inv(unsigned int key) {
    unsigned int b = (key & 0x80000000u) ? (key ^ 0x80000000u) : ~key;
    return __uint_as_float(b);
}

// ---------------- Kernel 1: argmin(usages) (single block) ----------------
__global__ __launch_bounds__(1024) void k_argmin(const float* __restrict__ usages,
                                                 float* __restrict__ W) {
    __shared__ unsigned long long s[1024];
    int t = threadIdx.x;
    unsigned long long best = ~0ULL;
    #pragma unroll
    for (int i = 0; i < KP / 1024; i++) {
        int j = t + i * 1024;
        unsigned long long p = ((unsigned long long)fkey(usages[j]) << 32) | (unsigned int)j;
        if (p < best) best = p;  // min; equal key -> smaller j wins (first occurrence)
    }
    s[t] = best;
    __syncthreads();
    for (int off = 512; off >= 1; off >>= 1) {
        if (t < off) { if (s[t + off] < s[t]) s[t] = s[t + off]; }
        __syncthreads();
    }
    if (t == 0) ((int*)W)[2] = (int)(s[0] & 0xFFFFFFFFu);
}

// ---- Kernel 2: fused dot-products + speculative evict copy (one wave/row) ----
// Store path v2: NO LDS round-trip. Output rows start at byte offset 12 mod 16,
// so out elements e==1 (mod 4) are 16B-aligned. Each lane already holds the
// aligned input float4s (needed for the dot products); the shifted output chunk
// {4c+1..4c+4} is {v.y, v.z, v.w, shfl_down(v.x)} -> 8 dense dwordx4 stores/row
// (1 KB/instr) instead of 32 dword stores via LDS.
// Stores are NON-TEMPORAL: the out stream is write-once, and letting it
// allocate in L3 evicts half of P (134 MB) per iteration -> the measured
// FETCH_SIZE == P/2. nt keeps P L3-resident.
__global__ __launch_bounds__(256) void k_dots_copy(const float* __restrict__ z,
                                                   const float* __restrict__ P,
                                                   const float* __restrict__ temp,
                                                   float* __restrict__ W,
                                                   float* __restrict__ out) {
    const int wave = threadIdx.x >> 6;
    const int lane = threadIdx.x & 63;
    const int r = blockIdx.x * 4 + wave;
    const int idx = ((const int*)W)[2];

    const float* prow = P + (size_t)r * DP;

    f4 v[8];
    float zp = 0.f, pp = 0.f, zz = 0.f;
    #pragma unroll
    for (int i = 0; i < 8; i++) {
        const int c = i * 256 + lane * 4;
        const f4 pv = *(const f4*)(prow + c);
        const f4 zv = *(const f4*)(z + c);
        v[i] = pv;
        zp += pv.x * zv.x + pv.y * zv.y + pv.z * zv.z + pv.w * zv.w;
        pp += pv.x * pv.x + pv.y * pv.y + pv.z * pv.z + pv.w * pv.w;
        zz += zv.x * zv.x + zv.y * zv.y + zv.z * zv.z + zv.w * zv.w;
    }

    // Speculative evict-layout copy: in-row r -> out-row (r<idx ? r : r-1), row idx dropped.
    // (If the EMA branch is taken, k_ema rewrites every out row from pristine d_in.)
    if (r != idx) {
        const int ro = (r < idx) ? r : r - 1;
        float* orow = out + 3 + (size_t)ro * DP;
        if (lane == 0) __builtin_nontemporal_store(v[0].x, orow);  // element 0
        #pragma unroll
        for (int i = 0; i < 8; i++) {
            float nx = __shfl_down(v[i].x, 1);            // lane l -> lane l+1's .x
            const float bx = __shfl(v[(i + 1) & 7].x, 0); // lane 63 -> next iter, lane 0
            if (lane == 63) nx = bx;
            f4 ov;
            ov.x = v[i].y; ov.y = v[i].z; ov.z = v[i].w; ov.w = nx;
            if (i < 7 || lane < 63) {  // chunk 511 would run past the row
                __builtin_nontemporal_store(ov, (f4*)(orow + 1 + 4 * (i * 64 + lane)));
            }
        }
        if (lane == 63) {  // tail elements 2045..2047 (byte-aligned to 16 at 2045)
            f2 t2; t2.x = v[7].y; t2.y = v[7].z;
            __builtin_nontemporal_store(t2, (f2*)(orow + DP - 3));
            __builtin_nontemporal_store(v[7].w, orow + DP - 1);
        }
    }

    zp = waveReduceSum(zp);
    pp = waveReduceSum(pp);
    zz = waveReduceSum(zz);
    if (lane == 0) {
        W[8 + r]          = temp[0] * zp / sqrtf(zz * pp);  // logit
        W[8 + KP + r]     = zp;
        W[8 + 2 * KP + r] = pp;
        if (r == 0) W[7] = zz;
    }
}

// ------- Kernel 3: scalars + reductions + evict epilogue (single block) -------
__global__ __launch_bounds__(1024) void k_scalar(const float* __restrict__ z,
                                                 const float* __restrict__ usages,
                                                 const float* __restrict__ beta,
                                                 const float* __restrict__ gamma,
                                                 const float* __restrict__ temp,
                                                 float* __restrict__ W,
                                                 float* __restrict__ out) {
    __shared__ float sf[1024];
    __shared__ unsigned long long sp[1024];
    const int t = threadIdx.x;
    const int idx = ((const int*)W)[2];

    float lg[KP / 1024];
    float mx_all = -INFINITY;
    unsigned long long bestx = 0;  // packed (key<<32)|~j, argmax excluding idx
    #pragma unroll
    for (int i = 0; i < KP / 1024; i++) {
        const int j = t + i * 1024;
        const float v = W[8 + j];
        lg[i] = v;
        mx_all = fmaxf(mx_all, v);
        if (j != idx) {
            unsigned long long p = ((unsigned long long)fkey(v) << 32) | (unsigned int)(~j);
            if (p > bestx) bestx = p;  // max; equal key -> larger ~j = smaller j wins
        }
    }
    sf[t] = mx_all;
    __syncthreads();
    for (int off = 512; off >= 1; off >>= 1) {
        if (t < off) sf[t] = fmaxf(sf[t], sf[t + off]);
        __syncthreads();
    }
    mx_all = sf[0];
    __syncthreads();

    const float u = 1.f / (1.f + expf(-((-mx_all - beta[0]) / gamma[0])));
    const int flag = (u >= THRESH) ? 1 : 0;  // uniform across block
    if (t == 0) {
        out[2] = u;
        ((int*)W)[3] = flag;
        W[4] = mx_all;
        W[6] = u;
    }

    if (flag) {
        // ---------- evict epilogue ----------
        sp[t] = bestx;
        __syncthreads();
        for (int off = 512; off >= 1; off >>= 1) {
            if (t < off) { if (sp[t + off] > sp[t]) sp[t] = sp[t + off]; }
            __syncthreads();
        }
        const unsigned long long bp = sp[0];
        const float mxe = fkey_inv((unsigned int)(bp >> 32));
        const int amax = (int)(~(unsigned int)(bp & 0xFFFFFFFFu));

        const float tq = temp[0];
        const float M2 = fmaxf(mxe, tq);
        float s = 0.f;
        #pragma unroll
        for (int i = 0; i < KP / 1024; i++) {
            const int j = t + i * 1024;
            if (j != idx) s += expf(lg[i] - M2);
        }
        sf[t] = s;
        __syncthreads();
        for (int off = 512; off >= 1; off >>= 1) {
            if (t < off) sf[t] += sf[t + off];
            __syncthreads();
        }
        if (t == 0) {
            const float total = sf[0] + expf(tq - M2);
            out[0] = logf(total);  // loss = logsumexp(l2) - max(l2); l2[label]==max
            const int label = (mxe >= tq) ? (amax < idx ? amax : amax - 1) : (KP - 1);
            out[1] = (float)label;
        }
        // new_usages = [usages[src]; 1.0] * DECAY
        float* ou = out + 3 + (size_t)KP * DP;
        #pragma unroll
        for (int i = 0; i < KP / 1024; i++) {
            const int j = t + i * 1024;
            ou[j] = (j < KP - 1) ? usages[j < idx ? j : j + 1] * DECAY : DECAY;
        }
        // new_protos last row = z
        float* orow = out + 3 + (size_t)(KP - 1) * DP;
        orow[t] = z[t];
        orow[t + 1024] = z[t + 1024];
    } else {
        // ---------- ema prep: softmax denominator ----------
        float s = 0.f;
        #pragma unroll
        for (int i = 0; i < KP / 1024; i++) s += expf(lg[i] - mx_all);
        sf[t] = s;
        __syncthreads();
        for (int off = 512; off >= 1; off >>= 1) {
            if (t < off) sf[t] += sf[t + off];
            __syncthreads();
        }
        if (t == 0) W[5] = sf[0];
    }
}

// --------- Kernel 4: EMA rewrite (early-exits in evict case) ---------
__global__ __launch_bounds__(256) void k_ema(const float* __restrict__ z,
                                             const float* __restrict__ P,
                                             const float* __restrict__ usages,
                                             const float* __restrict__ temp,
                                             float* __restrict__ W,
                                             float* __restrict__ out) {
    if (((const int*)W)[3]) return;  // evict branch taken -> nothing to do
    __shared__ float lds[4 * DP];
    const int wave = threadIdx.x >> 6;
    const int lane = threadIdx.x & 63;
    const int r = blockIdx.x * 4 + wave;

    const float mx = W[4], se = W[5], u = W[6], zz = W[7];
    const float lg = W[8 + r], zp = W[8 + KP + r], pp = W[8 + 2 * KP + r];
    const float y = expf(lg - mx) / se;
    const float delta = y * (1.f - u);
    const float usg = usages[r];
    const float a = delta / (delta + usg);
    const float b = usg / (usg + delta);

    const float* prow = P + (size_t)r * DP;
    float* wl = lds + wave * DP;
    float* orow = out + 3 + (size_t)r * DP;
    #pragma unroll
    for (int i = 0; i < 8; i++) {
        const int c = i * 256 + lane * 4;
        const float4 pv = *(const float4*)(prow + c);
        const float4 zv = *(const float4*)(z + c);
        float4 ov;
        ov.x = a * zv.x + b * pv.x;
        ov.y = a * zv.y + b * pv.y;
        ov.z = a * zv.z + b * pv.z;
        ov.w = a * zv.w + b * pv.w;
        *(float4*)(wl + c) = ov;
    }
    #pragma unroll
    for (int j = 0; j < DP / 64; j++) {
        orow[j * 64 + lane] = wl[j * 64 + lane];  // dense 256B per store instr
    }
    if (lane == 0) {
        // logits2 analytically: new_p = a*z + b*p
        const float dzn = a * zz + b * zp;          // z . new_p
        const float n2 = a * a * zz + 2.f * a * b * zp + b * b * pp;  // ||new_p||^2
        W[8 + 3 * KP + r] = temp[0] * dzn / sqrtf(zz * n2);
        out[3 + (size_t)KP * DP + r] = (usg + delta) * DECAY;
    }
}

// --------- Kernel 5: EMA loss/label (early-exits in evict case) ---------
__global__ __launch_bounds__(1024) void k_ema_loss(const float* __restrict__ W,
                                                   float* __restrict__ out) {
    if (((const int*)W)[3]) return;
    __shared__ unsigned long long sp[1024];
    __shared__ float sf[1024];
    const int t = threadIdx.x;

    float l2[KP / 1024];
    unsigned long long best = 0;
    #pragma unroll
    for (int i = 0; i < KP / 1024; i++) {
        const int j = t + i * 1024;
        const float v = W[8 + 3 * KP + j];
        l2[i] = v;
        unsigned long long p = ((unsigned long long)fkey(v) << 32) | (unsigned int)(~j);
        if (p > best) best = p;
    }
    sp[t] = best;
    __syncthreads();
    for (int off = 512; off >= 1; off >>= 1) {
        if (t < off) { if (sp[t + off] > sp[t]) sp[t] = sp[t + off]; }
        __syncthreads();
    }
    const unsigned long long bp = sp[0];
    const float mx = fkey_inv((unsigned int)(bp >> 32));
    const int label = (int)(~(unsigned int)(bp & 0xFFFFFFFFu));

    float s = 0.f;
    #pragma unroll
    for (int i = 0; i < KP / 1024; i++) s += expf(l2[i] - mx);
    __syncthreads();
    sf[t] = s;
    __syncthreads();
    for (int off = 512; off >= 1; off >>= 1) {
        if (t < off) sf[t] += sf[t + off];
        __syncthreads();
    }
    if (t == 0) {
        out[0] = logf(sf[0]);  // l2[label] == mx
        out[1] = (float)label;
    }
}

extern "C" void kernel_launch(void* const* d_in, const int* in_sizes, int n_in,
                              void* d_out, int out_size, void* d_ws, size_t ws_size,
                              hipStream_t stream) {
    const float* z      = (const float*)d_in[0];
    const float* P      = (const float*)d_in[1];
    const float* usages = (const float*)d_in[2];
    const float* beta   = (const float*)d_in[3];
    const float* gamma  = (const float*)d_in[4];
    const float* temp   = (const float*)d_in[5];
    float* out = (float*)d_out;
    float* W   = (float*)d_ws;  // needs (8 + 4*KP)*4 = 262176 bytes

    k_argmin<<<1, 1024, 0, stream>>>(usages, W);
    k_dots_copy<<<KP / 4, 256, 0, stream>>>(z, P, temp, W, out);
    k_scalar<<<1, 1024, 0, stream>>>(z, usages, beta, gamma, temp, W, out);
    k_ema<<<KP / 4, 256, 0, stream>>>(z, P, usages, temp, W, out);
    k_ema_loss<<<1, 1024, 0, stream>>>(W, out);
}

// Round 2
// 254.584 us; speedup vs baseline: 1.0588x; 1.0588x over previous
//
#include <hip/hip_runtime.h>
#include <math.h>

// Problem constants (static shapes per reference)
#define KP 16384
#define DP 2048
#define THRESH 0.5f
#define DECAY 0.99f

// ws float layout:
// [2]  (int) idxMin  = argmin(usages)
// [3]  (int) flag    = 1 evict, 0 ema
// [4]  max_all (max of logits)
// [5]  sumexp_all (ema softmax denom, exp(l - max_all))
// [6]  u
// [7]  zz = ||z||^2
// [8          .. 8+K)    logits
// [8+K        .. 8+2K)   zp (z . p_row)
// [8+2K       .. 8+3K)   pp (||p_row||^2)
// [8+3K       .. 8+4K)   logits2 (ema path only)
// total: (8 + 4*16384)*4 = 262176 bytes

typedef float f4 __attribute__((ext_vector_type(4)));
typedef float f2 __attribute__((ext_vector_type(2)));

__device__ __forceinline__ float waveReduceSum(float v) {
    #pragma unroll
    for (int m = 32; m >= 1; m >>= 1) v += __shfl_xor(v, m, 64);
    return v;
}

__device__ __forceinline__ unsigned int fkey(float v) {
    // monotone float->uint key (order-preserving for all finite floats)
    unsigned int b = __float_as_uint(v);
    return (b & 0x80000000u) ? ~b : (b | 0x80000000u);
}
__device__ __forceinline__ float fkey_inv(unsigned int key) {
    unsigned int b = (key & 0x80000000u) ? (key ^ 0x80000000u) : ~key;
    return __uint_as_float(b);
}

// ---------------- Kernel 1: argmin(usages) (single block) ----------------
__global__ __launch_bounds__(1024) void k_argmin(const float* __restrict__ usages,
                                                 float* __restrict__ W) {
    __shared__ unsigned long long s[1024];
    int t = threadIdx.x;
    unsigned long long best = ~0ULL;
    #pragma unroll
    for (int i = 0; i < KP / 1024; i++) {
        int j = t + i * 1024;
        unsigned long long p = ((unsigned long long)fkey(usages[j]) << 32) | (unsigned int)j;
        if (p < best) best = p;  // min; equal key -> smaller j wins (first occurrence)
    }
    s[t] = best;
    __syncthreads();
    for (int off = 512; off >= 1; off >>= 1) {
        if (t < off) { if (s[t + off] < s[t]) s[t] = s[t + off]; }
        __syncthreads();
    }
    if (t == 0) ((int*)W)[2] = (int)(s[0] & 0xFFFFFFFFu);
}

// ---- Kernel 2: fused dot-products + speculative evict copy (one wave/row) ----
// Store path v3: register-shuffle realignment (no LDS), PLAIN stores.
//   R0 (LDS + 32 dword stores)              : 79.5 us
//   R1 (reg-shuffle + nt dwordx4 stores)    : 81.8 us
//   -> store mechanism is NOT the bottleneck; plain stores let L2 merge the
//      4-byte-shifted partial lines, nt gave nothing.
// Load path v3: NON-TEMPORAL loads on P. Theory: the harness's 2x512MiB
// poison fills leave the 256MB MALL full of dirty lines; P read-misses then
// evict dirty poison -> HBM writebacks charged to this kernel's wall clock
// (observed FETCH == P/2 shows P and the out-stream fight for MALL capacity).
// nt loads keep P from allocating -> read path stops paying the eviction tax.
__global__ __launch_bounds__(256) void k_dots_copy(const float* __restrict__ z,
                                                   const float* __restrict__ P,
                                                   const float* __restrict__ temp,
                                                   float* __restrict__ W,
                                                   float* __restrict__ out) {
    const int wave = threadIdx.x >> 6;
    const int lane = threadIdx.x & 63;
    const int r = blockIdx.x * 4 + wave;
    const int idx = ((const int*)W)[2];

    const float* prow = P + (size_t)r * DP;

    f4 v[8];
    float zp = 0.f, pp = 0.f, zz = 0.f;
    #pragma unroll
    for (int i = 0; i < 8; i++) {
        const int c = i * 256 + lane * 4;
        const f4 pv = __builtin_nontemporal_load((const f4*)(prow + c));
        const f4 zv = *(const f4*)(z + c);
        v[i] = pv;
        zp += pv.x * zv.x + pv.y * zv.y + pv.z * zv.z + pv.w * zv.w;
        pp += pv.x * pv.x + pv.y * pv.y + pv.z * pv.z + pv.w * pv.w;
        zz += zv.x * zv.x + zv.y * zv.y + zv.z * zv.z + zv.w * zv.w;
    }

    // Speculative evict-layout copy: in-row r -> out-row (r<idx ? r : r-1), row idx dropped.
    // (If the EMA branch is taken, k_ema rewrites every out row from pristine d_in.)
    if (r != idx) {
        const int ro = (r < idx) ? r : r - 1;
        float* orow = out + 3 + (size_t)ro * DP;
        if (lane == 0) orow[0] = v[0].x;  // element 0
        #pragma unroll
        for (int i = 0; i < 8; i++) {
            float nx = __shfl_down(v[i].x, 1);            // lane l -> lane l+1's .x
            const float bx = __shfl(v[(i + 1) & 7].x, 0); // lane 63 -> next iter, lane 0
            if (lane == 63) nx = bx;
            f4 ov;
            ov.x = v[i].y; ov.y = v[i].z; ov.z = v[i].w; ov.w = nx;
            if (i < 7 || lane < 63) {  // chunk 511 would run past the row
                *(f4*)(orow + 1 + 4 * (i * 64 + lane)) = ov;
            }
        }
        if (lane == 63) {  // tail elements 2045..2047 (16B-aligned at 2045? no: 8B at 2045)
            f2 t2; t2.x = v[7].y; t2.y = v[7].z;
            *(f2*)(orow + DP - 3) = t2;
            orow[DP - 1] = v[7].w;
        }
    }

    zp = waveReduceSum(zp);
    pp = waveReduceSum(pp);
    zz = waveReduceSum(zz);
    if (lane == 0) {
        W[8 + r]          = temp[0] * zp / sqrtf(zz * pp);  // logit
        W[8 + KP + r]     = zp;
        W[8 + 2 * KP + r] = pp;
        if (r == 0) W[7] = zz;
    }
}

// ------- Kernel 3: scalars + reductions + evict epilogue (single block) -------
__global__ __launch_bounds__(1024) void k_scalar(const float* __restrict__ z,
                                                 const float* __restrict__ usages,
                                                 const float* __restrict__ beta,
                                                 const float* __restrict__ gamma,
                                                 const float* __restrict__ temp,
                                                 float* __restrict__ W,
                                                 float* __restrict__ out) {
    __shared__ float sf[1024];
    __shared__ unsigned long long sp[1024];
    const int t = threadIdx.x;
    const int idx = ((const int*)W)[2];

    float lg[KP / 1024];
    float mx_all = -INFINITY;
    unsigned long long bestx = 0;  // packed (key<<32)|~j, argmax excluding idx
    #pragma unroll
    for (int i = 0; i < KP / 1024; i++) {
        const int j = t + i * 1024;
        const float v = W[8 + j];
        lg[i] = v;
        mx_all = fmaxf(mx_all, v);
        if (j != idx) {
            unsigned long long p = ((unsigned long long)fkey(v) << 32) | (unsigned int)(~j);
            if (p > bestx) bestx = p;  // max; equal key -> larger ~j = smaller j wins
        }
    }
    sf[t] = mx_all;
    __syncthreads();
    for (int off = 512; off >= 1; off >>= 1) {
        if (t < off) sf[t] = fmaxf(sf[t], sf[t + off]);
        __syncthreads();
    }
    mx_all = sf[0];
    __syncthreads();

    const float u = 1.f / (1.f + expf(-((-mx_all - beta[0]) / gamma[0])));
    const int flag = (u >= THRESH) ? 1 : 0;  // uniform across block
    if (t == 0) {
        out[2] = u;
        ((int*)W)[3] = flag;
        W[4] = mx_all;
        W[6] = u;
    }

    if (flag) {
        // ---------- evict epilogue ----------
        sp[t] = bestx;
        __syncthreads();
        for (int off = 512; off >= 1; off >>= 1) {
            if (t < off) { if (sp[t + off] > sp[t]) sp[t] = sp[t + off]; }
            __syncthreads();
        }
        const unsigned long long bp = sp[0];
        const float mxe = fkey_inv((unsigned int)(bp >> 32));
        const int amax = (int)(~(unsigned int)(bp & 0xFFFFFFFFu));

        const float tq = temp[0];
        const float M2 = fmaxf(mxe, tq);
        float s = 0.f;
        #pragma unroll
        for (int i = 0; i < KP / 1024; i++) {
            const int j = t + i * 1024;
            if (j != idx) s += expf(lg[i] - M2);
        }
        sf[t] = s;
        __syncthreads();
        for (int off = 512; off >= 1; off >>= 1) {
            if (t < off) sf[t] += sf[t + off];
            __syncthreads();
        }
        if (t == 0) {
            const float total = sf[0] + expf(tq - M2);
            out[0] = logf(total);  // loss = logsumexp(l2) - max(l2); l2[label]==max
            const int label = (mxe >= tq) ? (amax < idx ? amax : amax - 1) : (KP - 1);
            out[1] = (float)label;
        }
        // new_usages = [usages[src]; 1.0] * DECAY
        float* ou = out + 3 + (size_t)KP * DP;
        #pragma unroll
        for (int i = 0; i < KP / 1024; i++) {
            const int j = t + i * 1024;
            ou[j] = (j < KP - 1) ? usages[j < idx ? j : j + 1] * DECAY : DECAY;
        }
        // new_protos last row = z
        float* orow = out + 3 + (size_t)(KP - 1) * DP;
        orow[t] = z[t];
        orow[t + 1024] = z[t + 1024];
    } else {
        // ---------- ema prep: softmax denominator ----------
        float s = 0.f;
        #pragma unroll
        for (int i = 0; i < KP / 1024; i++) s += expf(lg[i] - mx_all);
        sf[t] = s;
        __syncthreads();
        for (int off = 512; off >= 1; off >>= 1) {
            if (t < off) sf[t] += sf[t + off];
            __syncthreads();
        }
        if (t == 0) W[5] = sf[0];
    }
}

// --------- Kernel 4: EMA rewrite (early-exits in evict case) ---------
__global__ __launch_bounds__(256) void k_ema(const float* __restrict__ z,
                                             const float* __restrict__ P,
                                             const float* __restrict__ usages,
                                             const float* __restrict__ temp,
                                             float* __restrict__ W,
                                             float* __restrict__ out) {
    if (((const int*)W)[3]) return;  // evict branch taken -> nothing to do
    __shared__ float lds[4 * DP];
    const int wave = threadIdx.x >> 6;
    const int lane = threadIdx.x & 63;
    const int r = blockIdx.x * 4 + wave;

    const float mx = W[4], se = W[5], u = W[6], zz = W[7];
    const float lg = W[8 + r], zp = W[8 + KP + r], pp = W[8 + 2 * KP + r];
    const float y = expf(lg - mx) / se;
    const float delta = y * (1.f - u);
    const float usg = usages[r];
    const float a = delta / (delta + usg);
    const float b = usg / (usg + delta);

    const float* prow = P + (size_t)r * DP;
    float* wl = lds + wave * DP;
    float* orow = out + 3 + (size_t)r * DP;
    #pragma unroll
    for (int i = 0; i < 8; i++) {
        const int c = i * 256 + lane * 4;
        const float4 pv = *(const float4*)(prow + c);
        const float4 zv = *(const float4*)(z + c);
        float4 ov;
        ov.x = a * zv.x + b * pv.x;
        ov.y = a * zv.y + b * pv.y;
        ov.z = a * zv.z + b * pv.z;
        ov.w = a * zv.w + b * pv.w;
        *(float4*)(wl + c) = ov;
    }
    #pragma unroll
    for (int j = 0; j < DP / 64; j++) {
        orow[j * 64 + lane] = wl[j * 64 + lane];  // dense 256B per store instr
    }
    if (lane == 0) {
        // logits2 analytically: new_p = a*z + b*p
        const float dzn = a * zz + b * zp;          // z . new_p
        const float n2 = a * a * zz + 2.f * a * b * zp + b * b * pp;  // ||new_p||^2
        W[8 + 3 * KP + r] = temp[0] * dzn / sqrtf(zz * n2);
        out[3 + (size_t)KP * DP + r] = (usg + delta) * DECAY;
    }
}

// --------- Kernel 5: EMA loss/label (early-exits in evict case) ---------
__global__ __launch_bounds__(1024) void k_ema_loss(const float* __restrict__ W,
                                                   float* __restrict__ out) {
    if (((const int*)W)[3]) return;
    __shared__ unsigned long long sp[1024];
    __shared__ float sf[1024];
    const int t = threadIdx.x;

    float l2[KP / 1024];
    unsigned long long best = 0;
    #pragma unroll
    for (int i = 0; i < KP / 1024; i++) {
        const int j = t + i * 1024;
        const float v = W[8 + 3 * KP + j];
        l2[i] = v;
        unsigned long long p = ((unsigned long long)fkey(v) << 32) | (unsigned int)(~j);
        if (p > best) best = p;
    }
    sp[t] = best;
    __syncthreads();
    for (int off = 512; off >= 1; off >>= 1) {
        if (t < off) { if (sp[t + off] > sp[t]) sp[t] = sp[t + off]; }
        __syncthreads();
    }
    const unsigned long long bp = sp[0];
    const float mx = fkey_inv((unsigned int)(bp >> 32));
    const int label = (int)(~(unsigned int)(bp & 0xFFFFFFFFu));

    float s = 0.f;
    #pragma unroll
    for (int i = 0; i < KP / 1024; i++) s += expf(l2[i] - mx);
    __syncthreads();
    sf[t] = s;
    __syncthreads();
    for (int off = 512; off >= 1; off >>= 1) {
        if (t < off) sf[t] += sf[t + off];
        __syncthreads();
    }
    if (t == 0) {
        out[0] = logf(sf[0]);  // l2[label] == mx
        out[1] = (float)label;
    }
}

extern "C" void kernel_launch(void* const* d_in, const int* in_sizes, int n_in,
                              void* d_out, int out_size, void* d_ws, size_t ws_size,
                              hipStream_t stream) {
    const float* z      = (const float*)d_in[0];
    const float* P      = (const float*)d_in[1];
    const float* usages = (const float*)d_in[2];
    const float* beta   = (const float*)d_in[3];
    const float* gamma  = (const float*)d_in[4];
    const float* temp   = (const float*)d_in[5];
    float* out = (float*)d_out;
    float* W   = (float*)d_ws;  // needs (8 + 4*KP)*4 = 262176 bytes

    k_argmin<<<1, 1024, 0, stream>>>(usages, W);
    k_dots_copy<<<KP / 4, 256, 0, stream>>>(z, P, temp, W, out);
    k_scalar<<<1, 1024, 0, stream>>>(z, usages, beta, gamma, temp, W, out);
    k_ema<<<KP / 4, 256, 0, stream>>>(z, P, usages, temp, W, out);
    k_ema_loss<<<1, 1024, 0, stream>>>(W, out);
}

// Round 3
// 253.475 us; speedup vs baseline: 1.0635x; 1.0044x over previous
//
#include <hip/hip_runtime.h>
#include <math.h>

// Problem constants (static shapes per reference)
#define KP 16384
#define DP 2048
#define THRESH 0.5f
#define DECAY 0.99f

// ws float layout:
// [2]  (int) idxMin  = argmin(usages)
// [3]  (int) flag    = 1 evict, 0 ema
// [4]  max_all (max of logits)
// [5]  sumexp_all (ema softmax denom, exp(l - max_all))
// [6]  u
// [7]  zz = ||z||^2
// [8          .. 8+K)    logits
// [8+K        .. 8+2K)   zp (z . p_row)
// [8+2K       .. 8+3K)   pp (||p_row||^2)
// [8+3K       .. 8+4K)   logits2 (ema path only)
// total: (8 + 4*16384)*4 = 262176 bytes

typedef float f4 __attribute__((ext_vector_type(4)));
typedef float f2 __attribute__((ext_vector_type(2)));
typedef unsigned long long u64;

__device__ __forceinline__ float waveReduceSum(float v) {
    #pragma unroll
    for (int m = 32; m >= 1; m >>= 1) v += __shfl_xor(v, m, 64);
    return v;
}

__device__ __forceinline__ unsigned int fkey(float v) {
    // monotone float->uint key (order-preserving for all finite floats)
    unsigned int b = __float_as_uint(v);
    return (b & 0x80000000u) ? ~b : (b | 0x80000000u);
}
__device__ __forceinline__ float fkey_inv(unsigned int key) {
    unsigned int b = (key & 0x80000000u) ? (key ^ 0x80000000u) : ~key;
    return __uint_as_float(b);
}

// ---------------- Kernel 1: argmin(usages) (single block) ----------------
// v3: shfl-butterfly min (order-safe packed keys) -> 2 barriers instead of 10.
__global__ __launch_bounds__(1024) void k_argmin(const float* __restrict__ usages,
                                                 float* __restrict__ W) {
    __shared__ u64 s[16];
    const int t = threadIdx.x;
    u64 best = ~0ULL;
    #pragma unroll
    for (int i = 0; i < KP / 1024; i++) {
        const int j = t + i * 1024;
        u64 p = ((u64)fkey(usages[j]) << 32) | (unsigned int)j;
        if (p < best) best = p;  // min; equal key -> smaller j wins (first occurrence)
    }
    #pragma unroll
    for (int m = 32; m >= 1; m >>= 1) {
        u64 o = __shfl_xor(best, m, 64);
        if (o < best) best = o;
    }
    if ((t & 63) == 0) s[t >> 6] = best;
    __syncthreads();
    if (t < 64) {  // whole wave active; values repeat every 16 lanes
        best = s[t & 15];
        #pragma unroll
        for (int m = 8; m >= 1; m >>= 1) {
            u64 o = __shfl_xor(best, m, 64);
            if (o < best) best = o;
        }
        if (t == 0) ((int*)W)[2] = (int)(best & 0xFFFFFFFFu);
    }
}

// ---- Kernel 2: fused dot-products + speculative evict copy (one wave/row) ----
// Load path (R2, kept): NON-TEMPORAL loads on P -> -15us. Theory: harness's
// poison fills leave MALL full of dirty lines; allocating P evicts dirty
// poison -> HBM writebacks on our clock. nt loads dodge the tax.
// Store path v4: nt STORES re-added now that loads are nt. R1 tested nt
// stores with ALLOCATING loads (neutral: read path still paid the tax,
// masking the store side). If the MALL theory is right they stack; if
// k_dots_copy is unchanged, ~4 TB/s is the mixed-stream floor.
__global__ __launch_bounds__(256) void k_dots_copy(const float* __restrict__ z,
                                                   const float* __restrict__ P,
                                                   const float* __restrict__ temp,
                                                   float* __restrict__ W,
                                                   float* __restrict__ out) {
    const int wave = threadIdx.x >> 6;
    const int lane = threadIdx.x & 63;
    const int r = blockIdx.x * 4 + wave;
    const int idx = ((const int*)W)[2];

    const float* prow = P + (size_t)r * DP;

    f4 v[8];
    float zp = 0.f, pp = 0.f, zz = 0.f;
    #pragma unroll
    for (int i = 0; i < 8; i++) {
        const int c = i * 256 + lane * 4;
        const f4 pv = __builtin_nontemporal_load((const f4*)(prow + c));
        const f4 zv = *(const f4*)(z + c);
        v[i] = pv;
        zp += pv.x * zv.x + pv.y * zv.y + pv.z * zv.z + pv.w * zv.w;
        pp += pv.x * pv.x + pv.y * pv.y + pv.z * pv.z + pv.w * pv.w;
        zz += zv.x * zv.x + zv.y * zv.y + zv.z * zv.z + zv.w * zv.w;
    }

    // Speculative evict-layout copy: in-row r -> out-row (r<idx ? r : r-1), row idx dropped.
    // (If the EMA branch is taken, k_ema rewrites every out row from pristine d_in.)
    if (r != idx) {
        const int ro = (r < idx) ? r : r - 1;
        float* orow = out + 3 + (size_t)ro * DP;
        if (lane == 0) __builtin_nontemporal_store(v[0].x, orow);  // element 0
        #pragma unroll
        for (int i = 0; i < 8; i++) {
            float nx = __shfl_down(v[i].x, 1);            // lane l -> lane l+1's .x
            const float bx = __shfl(v[(i + 1) & 7].x, 0); // lane 63 -> next iter, lane 0
            if (lane == 63) nx = bx;
            f4 ov;
            ov.x = v[i].y; ov.y = v[i].z; ov.z = v[i].w; ov.w = nx;
            if (i < 7 || lane < 63) {  // chunk 511 would run past the row
                __builtin_nontemporal_store(ov, (f4*)(orow + 1 + 4 * (i * 64 + lane)));
            }
        }
        if (lane == 63) {  // tail elements 2045..2047
            f2 t2; t2.x = v[7].y; t2.y = v[7].z;
            __builtin_nontemporal_store(t2, (f2*)(orow + DP - 3));
            __builtin_nontemporal_store(v[7].w, orow + DP - 1);
        }
    }

    zp = waveReduceSum(zp);
    pp = waveReduceSum(pp);
    zz = waveReduceSum(zz);
    if (lane == 0) {
        W[8 + r]          = temp[0] * zp / sqrtf(zz * pp);  // logit
        W[8 + KP + r]     = zp;
        W[8 + 2 * KP + r] = pp;
        if (r == 0) W[7] = zz;
    }
}

// ------- Kernel 3: scalars + reductions + evict epilogue (single block) -------
// v3: max/argmax reductions via shfl butterflies (order-safe: fmaxf and packed
// u64 max are associative/commutative, bit-exact regardless of order).
// SUM trees kept byte-identical to R0-R2 (summation order affects loss bits;
// absmax is 0.0 and stays that way).
__global__ __launch_bounds__(1024) void k_scalar(const float* __restrict__ z,
                                                 const float* __restrict__ usages,
                                                 const float* __restrict__ beta,
                                                 const float* __restrict__ gamma,
                                                 const float* __restrict__ temp,
                                                 float* __restrict__ W,
                                                 float* __restrict__ out) {
    __shared__ float sf[1024];
    __shared__ float sm[16];
    __shared__ u64 sb[16];
    const int t = threadIdx.x;
    const int idx = ((const int*)W)[2];

    float lg[KP / 1024];
    float mx_all = -INFINITY;
    u64 bestx = 0;  // packed (key<<32)|~j, argmax excluding idx
    #pragma unroll
    for (int i = 0; i < KP / 1024; i++) {
        const int j = t + i * 1024;
        const float v = W[8 + j];
        lg[i] = v;
        mx_all = fmaxf(mx_all, v);
        if (j != idx) {
            u64 p = ((u64)fkey(v) << 32) | (unsigned int)(~j);
            if (p > bestx) bestx = p;  // max; equal key -> larger ~j = smaller j wins
        }
    }
    // wave butterflies
    #pragma unroll
    for (int m = 32; m >= 1; m >>= 1) {
        mx_all = fmaxf(mx_all, __shfl_xor(mx_all, m, 64));
        u64 o = __shfl_xor(bestx, m, 64);
        if (o > bestx) bestx = o;
    }
    if ((t & 63) == 0) { sm[t >> 6] = mx_all; sb[t >> 6] = bestx; }
    __syncthreads();
    if (t < 64) {  // whole wave active; values repeat every 16 lanes
        float m = sm[t & 15];
        u64 b = sb[t & 15];
        #pragma unroll
        for (int mk = 8; mk >= 1; mk >>= 1) {
            m = fmaxf(m, __shfl_xor(m, mk, 64));
            u64 o = __shfl_xor(b, mk, 64);
            if (o > b) b = o;
        }
        if (t == 0) { sm[0] = m; sb[0] = b; }
    }
    __syncthreads();
    mx_all = sm[0];

    const float u = 1.f / (1.f + expf(-((-mx_all - beta[0]) / gamma[0])));
    const int flag = (u >= THRESH) ? 1 : 0;  // uniform across block
    if (t == 0) {
        out[2] = u;
        ((int*)W)[3] = flag;
        W[4] = mx_all;
        W[6] = u;
    }

    if (flag) {
        // ---------- evict epilogue ----------
        const u64 bp = sb[0];
        const float mxe = fkey_inv((unsigned int)(bp >> 32));
        const int amax = (int)(~(unsigned int)(bp & 0xFFFFFFFFu));

        const float tq = temp[0];
        const float M2 = fmaxf(mxe, tq);
        float s = 0.f;
        #pragma unroll
        for (int i = 0; i < KP / 1024; i++) {
            const int j = t + i * 1024;
            if (j != idx) s += expf(lg[i] - M2);
        }
        sf[t] = s;
        __syncthreads();
        for (int off = 512; off >= 1; off >>= 1) {
            if (t < off) sf[t] += sf[t + off];
            __syncthreads();
        }
        if (t == 0) {
            const float total = sf[0] + expf(tq - M2);
            out[0] = logf(total);  // loss = logsumexp(l2) - max(l2); l2[label]==max
            const int label = (mxe >= tq) ? (amax < idx ? amax : amax - 1) : (KP - 1);
            out[1] = (float)label;
        }
        // new_usages = [usages[src]; 1.0] * DECAY
        float* ou = out + 3 + (size_t)KP * DP;
        #pragma unroll
        for (int i = 0; i < KP / 1024; i++) {
            const int j = t + i * 1024;
            ou[j] = (j < KP - 1) ? usages[j < idx ? j : j + 1] * DECAY : DECAY;
        }
        // new_protos last row = z
        float* orow = out + 3 + (size_t)(KP - 1) * DP;
        orow[t] = z[t];
        orow[t + 1024] = z[t + 1024];
    } else {
        // ---------- ema prep: softmax denominator ----------
        float s = 0.f;
        #pragma unroll
        for (int i = 0; i < KP / 1024; i++) s += expf(lg[i] - mx_all);
        sf[t] = s;
        __syncthreads();
        for (int off = 512; off >= 1; off >>= 1) {
            if (t < off) sf[t] += sf[t + off];
            __syncthreads();
        }
        if (t == 0) W[5] = sf[0];
    }
}

// --------- Kernel 4: EMA rewrite (early-exits in evict case) ---------
__global__ __launch_bounds__(256) void k_ema(const float* __restrict__ z,
                                             const float* __restrict__ P,
                                             const float* __restrict__ usages,
                                             const float* __restrict__ temp,
                                             float* __restrict__ W,
                                             float* __restrict__ out) {
    if (((const int*)W)[3]) return;  // evict branch taken -> nothing to do
    __shared__ float lds[4 * DP];
    const int wave = threadIdx.x >> 6;
    const int lane = threadIdx.x & 63;
    const int r = blockIdx.x * 4 + wave;

    const float mx = W[4], se = W[5], u = W[6], zz = W[7];
    const float lg = W[8 + r], zp = W[8 + KP + r], pp = W[8 + 2 * KP + r];
    const float y = expf(lg - mx) / se;
    const float delta = y * (1.f - u);
    const float usg = usages[r];
    const float a = delta / (delta + usg);
    const float b = usg / (usg + delta);

    const float* prow = P + (size_t)r * DP;
    float* wl = lds + wave * DP;
    float* orow = out + 3 + (size_t)r * DP;
    #pragma unroll
    for (int i = 0; i < 8; i++) {
        const int c = i * 256 + lane * 4;
        const float4 pv = *(const float4*)(prow + c);
        const float4 zv = *(const float4*)(z + c);
        float4 ov;
        ov.x = a * zv.x + b * pv.x;
        ov.y = a * zv.y + b * pv.y;
        ov.z = a * zv.z + b * pv.z;
        ov.w = a * zv.w + b * pv.w;
        *(float4*)(wl + c) = ov;
    }
    #pragma unroll
    for (int j = 0; j < DP / 64; j++) {
        orow[j * 64 + lane] = wl[j * 64 + lane];  // dense 256B per store instr
    }
    if (lane == 0) {
        // logits2 analytically: new_p = a*z + b*p
        const float dzn = a * zz + b * zp;          // z . new_p
        const float n2 = a * a * zz + 2.f * a * b * zp + b * b * pp;  // ||new_p||^2
        W[8 + 3 * KP + r] = temp[0] * dzn / sqrtf(zz * n2);
        out[3 + (size_t)KP * DP + r] = (usg + delta) * DECAY;
    }
}

// --------- Kernel 5: EMA loss/label (early-exits in evict case) ---------
__global__ __launch_bounds__(1024) void k_ema_loss(const float* __restrict__ W,
                                                   float* __restrict__ out) {
    if (((const int*)W)[3]) return;
    __shared__ unsigned long long sp[1024];
    __shared__ float sf[1024];
    const int t = threadIdx.x;

    float l2[KP / 1024];
    u64 best = 0;
    #pragma unroll
    for (int i = 0; i < KP / 1024; i++) {
        const int j = t + i * 1024;
        const float v = W[8 + 3 * KP + j];
        l2[i] = v;
        u64 p = ((u64)fkey(v) << 32) | (unsigned int)(~j);
        if (p > best) best = p;
    }
    sp[t] = best;
    __syncthreads();
    for (int off = 512; off >= 1; off >>= 1) {
        if (t < off) { if (sp[t + off] > sp[t]) sp[t] = sp[t + off]; }
        __syncthreads();
    }
    const u64 bp = sp[0];
    const float mx = fkey_inv((unsigned int)(bp >> 32));
    const int label = (int)(~(unsigned int)(bp & 0xFFFFFFFFu));

    float s = 0.f;
    #pragma unroll
    for (int i = 0; i < KP / 1024; i++) s += expf(l2[i] - mx);
    __syncthreads();
    sf[t] = s;
    __syncthreads();
    for (int off = 512; off >= 1; off >>= 1) {
        if (t < off) sf[t] += sf[t + off];
        __syncthreads();
    }
    if (t == 0) {
        out[0] = logf(sf[0]);  // l2[label] == mx
        out[1] = (float)label;
    }
}

extern "C" void kernel_launch(void* const* d_in, const int* in_sizes, int n_in,
                              void* d_out, int out_size, void* d_ws, size_t ws_size,
                              hipStream_t stream) {
    const float* z      = (const float*)d_in[0];
    const float* P      = (const float*)d_in[1];
    const float* usages = (const float*)d_in[2];
    const float* beta   = (const float*)d_in[3];
    const float* gamma  = (const float*)d_in[4];
    const float* temp   = (const float*)d_in[5];
    float* out = (float*)d_out;
    float* W   = (float*)d_ws;  // needs (8 + 4*KP)*4 = 262176 bytes

    k_argmin<<<1, 1024, 0, stream>>>(usages, W);
    k_dots_copy<<<KP / 4, 256, 0, stream>>>(z, P, temp, W, out);
    k_scalar<<<1, 1024, 0, stream>>>(z, usages, beta, gamma, temp, W, out);
    k_ema<<<KP / 4, 256, 0, stream>>>(z, P, usages, temp, W, out);
    k_ema_loss<<<1, 1024, 0, stream>>>(W, out);
}